// Round 7
// baseline (5588721.094 us; speedup 1.0000x reference)
//
#include <hip/hip_runtime.h>
#include <math.h>

// ---------------------------------------------------------------------------
// RNN knowledge-tracing model, MI355X (gfx950).
// B=64, T=200, SKILLS=1024, C=256, H=1024.  ALL external I/O is fp32.
// Internal compute uses bf16 MFMA with fp32 accumulation.
// Round 12: XCD-LOCAL exchange.  r5-r11 showed the scan is bound by ~3.5
// serial device-coherence round trips per step (~1500-2000 cy each at the
// IC); protocol restructures move +-10%.  This round shrinks the DISTANCE:
//   * 8 batch-groups x 8 batches; group g = blocks with blockIdx%8 == g
//     (256 blocks x 512 thr, 32 col-groups/group).  Under the round-robin
//     block->XCD dispatch (blockIdx%8), a whole group shares ONE XCD/L2.
//   * Runtime placement check: each block reads HW_REG_XCC_ID into a
//     directory; each group verifies uniformity (bounded poll).
//     Uniform -> LOCAL mode: plain stores (vmcnt ack = L2 = the shared
//       visibility point), sc0-only loads (bypass L1, read shared L2).
//       Every exchange hop ~200-400 cy instead of ~1500-2000.
//     Non-uniform -> AGENT mode: r8's proven protocol (returning
//       exchanges -> vmcnt -> flag; sc0 sc1 staging) — correct anywhere.
//   * M=8 MFMA tiles (rows 8-15 duplicated/discarded): MFMA was ~10% of
//     step time; staged bytes per block halve to 16KB.
//   * Bounded spins: any pathology ends as a readable absmax failure.
//   * dir[] aliases the dead kcv region, zeroed by init2 after the gx GEMM.
// ---------------------------------------------------------------------------

typedef unsigned short u16;
typedef unsigned long long u64;
typedef __bf16 bf16x8 __attribute__((ext_vector_type(8)));
typedef float floatx4 __attribute__((ext_vector_type(4)));
typedef unsigned int u32x4 __attribute__((ext_vector_type(4)));

__device__ __forceinline__ float bf2f(u16 h) {
  unsigned int u = ((unsigned int)h) << 16;
  float f;
  __builtin_memcpy(&f, &u, 4);
  return f;
}
__device__ __forceinline__ u16 f2bf(float f) {
  unsigned int u;
  __builtin_memcpy(&u, &f, 4);
  u += 0x7FFFu + ((u >> 16) & 1u);  // RNE
  return (u16)(u >> 16);
}
__device__ __forceinline__ float sigm(float x) { return 1.0f / (1.0f + __expf(-x)); }

// --- fp32 -> bf16 convert, float4 vectorized; exact grid (n % 1024 == 0) ---
__global__ void cvt_kernel(const float* __restrict__ in, u16* __restrict__ out) {
  const int i = blockIdx.x * 256 + threadIdx.x;
  const float4 v = ((const float4*)in)[i];
  ushort4 o;
  o.x = f2bf(v.x);
  o.y = f2bf(v.y);
  o.z = f2bf(v.z);
  o.w = f2bf(v.w);
  ((ushort4*)out)[i] = o;
}

// ---------------------------------------------------------------------------
// Generic 128x128-tile bf16 GEMM, C = A[M,K] @ B[N,K]^T, epilogue functor.
// ---------------------------------------------------------------------------
template <class Epi>
__global__ __launch_bounds__(256, 2) void gemm_bt(const u16* __restrict__ A,
                                                  const u16* __restrict__ B,
                                                  int M, int N, int K, Epi epi) {
  __shared__ u16 As[128 * 32];
  __shared__ u16 Bs[128 * 32];
  const int tid = threadIdx.x;
  const int w = tid >> 6, lane = tid & 63;
  const int wm = w & 1, wn = w >> 1;
  const int bm = blockIdx.x * 128, bn = blockIdx.y * 128;
  const int lrow = lane & 15, lk8 = (lane >> 4) * 8;
  const int srow = lane >> 2;        // staging: row within 16-row segment
  const int skc = (lane & 3) * 8;    // staging: k chunk (8 bf16 = 16B)

  floatx4 acc[4][4] = {};

  for (int k0 = 0; k0 < K; k0 += 32) {
#pragma unroll
    for (int r = 0; r < 2; ++r) {
      const int seg = w * 2 + r;  // 8 segments of 16 rows x 32 k
      const int row = seg * 16 + srow;
      __builtin_amdgcn_global_load_lds(
          (const __attribute__((address_space(1))) unsigned int*)(A + (size_t)(bm + row) * K + k0 + skc),
          (__attribute__((address_space(3))) unsigned int*)(As + seg * 512), 16, 0, 0);
      __builtin_amdgcn_global_load_lds(
          (const __attribute__((address_space(1))) unsigned int*)(B + (size_t)(bn + row) * K + k0 + skc),
          (__attribute__((address_space(3))) unsigned int*)(Bs + seg * 512), 16, 0, 0);
    }
    __syncthreads();

    bf16x8 af[4], bfr[4];
#pragma unroll
    for (int i = 0; i < 4; ++i) {
      af[i] = *(const bf16x8*)(As + (wm * 64 + i * 16 + lrow) * 32 + lk8);
      bfr[i] = *(const bf16x8*)(Bs + (wn * 64 + i * 16 + lrow) * 32 + lk8);
    }
#pragma unroll
    for (int i = 0; i < 4; ++i)
#pragma unroll
      for (int j = 0; j < 4; ++j)
        acc[i][j] = __builtin_amdgcn_mfma_f32_16x16x32_bf16(af[i], bfr[j], acc[i][j], 0, 0, 0);
    __syncthreads();
  }

  // C/D layout: col = lane&15, row = (lane>>4)*4 + reg  [verified m89/m91]
  const int rbase = bm + wm * 64 + (lane >> 4) * 4;
  const int cbase = bn + wn * 64 + lrow;
#pragma unroll
  for (int i = 0; i < 4; ++i)
#pragma unroll
    for (int j = 0; j < 4; ++j)
#pragma unroll
      for (int r = 0; r < 4; ++r)
        epi(rbase + i * 16 + r, cbase + j * 16, acc[i][j][r]);
}

// --- epilogues --------------------------------------------------------------
struct EpiKcVec {  // rows are b*200+t; scatter into [row][512] by result mask
  const float* bkc;
  const int* result;
  u16* kcv;
  __device__ void operator()(int row, int col, float v) const {
    v += bkc[col];
    const int off = (result[row] == 1) ? 0 : 256;
    const size_t base = (size_t)row * 512;
    kcv[base + off + col] = f2bf(v);
    kcv[base + (256 - off) + col] = 0;  // zero half
  }
};
struct EpiNk {
  const float* bkc;
  float* nk;
  __device__ void operator()(int row, int col, float v) const {
    nk[(size_t)row * 256 + col] = v + bkc[col];
  }
};
struct EpiGx {  // input row = b*200+t -> store t-major (t*64+b), bf16
  const float* bih;
  const float* bhh;
  u16* gx;
  __device__ void operator()(int row, int col, float v) const {
    v += bih[col] + bhh[col];
    const int b = row / 200, t = row - b * 200;
    gx[(size_t)(t * 64 + b) * 4096 + col] = f2bf(v);
  }
};
struct EpiStu {  // input row = t*64+b -> store fp32 at (b*200+t)*256+col
  const float* bst;
  float* out;
  __device__ void operator()(int row, int col, float v) const {
    v += bst[col];
    const int b = row & 63, t = row >> 6;
    out[(size_t)(b * 200 + t) * 256 + col] = v;
  }
};

// ---------------------------------------------------------------------------
// init: zero h frame 0 (64x1024 bf16 = 128KB) + 256 flags
// ---------------------------------------------------------------------------
__global__ void init_kernel(u16* hseq, unsigned* flags) {
  const int i = blockIdx.x * 256 + threadIdx.x;  // 64 blocks -> 16384 threads
  ((u64*)hseq)[i] = 0ULL;
  if (blockIdx.x == 0) flags[threadIdx.x] = 0u;
}
// init2: zero the 256-entry XCD directory (aliases dead kcv; run AFTER EpiGx)
__global__ void init2_kernel(unsigned* dir) { dir[threadIdx.x] = 0u; }

// ---------------------------------------------------------------------------
// LSTM scan. 256 blocks x 512 threads = 8 batch-groups x 32 col-groups;
// group g = blocks with blockIdx%8 == g; block owns 8 batches x 32 h-cols.
// Wave w (0..7): gate = w>>1, col-half = w&1; W_hh slice (16 rows x 1024 K)
// in registers as 32 MFMA B-fragments.  M=8: MFMA rows 8-15 are duplicates
// of 0-7 and discarded.
//
// Exchange, two modes (per-group, decided once from the XCD directory):
//  LOCAL (group on one XCD/L2): publish = plain u64 stores (vmcnt ack = L2,
//        the shared visibility point); flag = plain store; poll + stage =
//        sc0-only loads (bypass L1, read shared L2).
//  AGENT (fallback, any placement): r8's proven protocol — returning
//        exchanges -> vmcnt(0) -> agent flag store; agent flag poll;
//        sc0 sc1 read-through staging.
// Barriers/step: post-poll, post-stage, post-gbuf, post-drain (4).
// ---------------------------------------------------------------------------
__global__ __launch_bounds__(512, 2) void lstm_scan(const u16* __restrict__ Whh,
                                                    const u16* __restrict__ gx,
                                                    u16* __restrict__ hseq,
                                                    unsigned* __restrict__ flags,
                                                    unsigned* __restrict__ dir) {
  __shared__ __align__(16) u16 Ab[8 * 1032];  // +8 pad per row
  __shared__ float gbuf[4 * 256];             // [gate][row 0..7][col 0..31]
  __shared__ int smode;
  const int tid = threadIdx.x;
  const int w = tid >> 6;
  const int lane = tid & 63;
  const int lrow = lane & 15;
  const int lk8 = (lane >> 4) * 8;
  const int gate = w >> 1;  // i,f,g,o
  const int half = w & 1;   // 16-col half of the block's 32 cols
  const int g = blockIdx.x & 7;      // batch-group == hoped XCD id
  const int slot = blockIdx.x >> 3;  // col-group 0..31
  const int bb = g * 8;
  const int j0 = slot * 32;

  // --- one-time placement discovery: is my group on a single XCD? ---
  {
    unsigned xcd;
    asm("s_getreg_b32 %0, hwreg(HW_REG_XCC_ID)" : "=s"(xcd));
    if (tid == 0)
      __hip_atomic_store(&dir[blockIdx.x], xcd + 1u, __ATOMIC_RELAXED,
                         __HIP_MEMORY_SCOPE_AGENT);
    if (w == 0) {
      const unsigned* dp = &dir[(lane & 31) * 8 + g];
      unsigned v = 0u;
      for (unsigned s = 0; s < (1u << 22); ++s) {
        v = __hip_atomic_load(dp, __ATOMIC_RELAXED, __HIP_MEMORY_SCOPE_AGENT);
        if (__all(v != 0u)) break;
        __builtin_amdgcn_s_sleep(2);
      }
      const unsigned v0 = (unsigned)__shfl((int)v, 0, 64);
      if (lane == 0) smode = __all(v == v0) ? 1 : 0;
    }
    __syncthreads();
  }
  const bool local = (smode != 0);

  // B-fragments: W_hh[gate*1024 + j0 + half*16 + lrow][k] -> 128 regs
  bf16x8 bfrag[32];
  {
    const u16* wp = Whh + (size_t)(gate * 1024 + j0 + half * 16 + lrow) * 1024 + lk8;
#pragma unroll
    for (int ks = 0; ks < 32; ++ks) bfrag[ks] = *(const bf16x8*)(wp + ks * 32);
  }

  float c_state = 0.0f;

  // gx: 4 values/thread; batch row base clamped to 0..7 (M=8 duplicates)
  const u16* gxb = gx + (size_t)(bb + (((lane >> 4) * 4) & 7)) * 4096 +
                   gate * 1024 + j0 + half * 16 + lrow;
  u16 gcur[4];
  {
    const u16* gp = gxb;  // t = 0
    gcur[0] = gp[0];
    gcur[1] = gp[4096];
    gcur[2] = gp[8192];
    gcur[3] = gp[12288];
  }

  for (int t = 0; t < 200; ++t) {
    // ---- wait: wave 0 polls the 32 member flags for >= t ----
    if (t > 0 && w == 0) {
      const unsigned tgt = (unsigned)t;
      const unsigned* fp = &flags[(lane & 31) * 8 + g];
      if (local) {
        for (unsigned s = 0; s < (1u << 18); ++s) {
          unsigned v;
          asm volatile("global_load_dword %0, %1, off sc0\n\ts_waitcnt vmcnt(0)"
                       : "=v"(v)
                       : "v"(fp)
                       : "memory");
          if (__all(v >= tgt)) break;
          __builtin_amdgcn_s_sleep(1);
        }
      } else {
        for (unsigned s = 0; s < (1u << 18); ++s) {
          const unsigned v = __hip_atomic_load(fp, __ATOMIC_RELAXED,
                                               __HIP_MEMORY_SCOPE_AGENT);
          if (__all(v >= tgt)) break;
          __builtin_amdgcn_s_sleep(1);
        }
      }
    }
    __syncthreads();

    // ---- stage h[t] rows bb..bb+7 (16KB): 2 x 16B coherent loads/thread ----
    {
      const char* hb = (const char*)(hseq + (size_t)t * 65536 + (size_t)bb * 1024);
      const char* p0 = hb + (tid >> 7) * 2048 + (tid & 127) * 16;
      const char* p1 = p0 + 8192;  // +4 rows
      u32x4 t0, t1;
      if (local) {
        asm volatile(
            "global_load_dwordx4 %0, %2, off sc0\n\t"
            "global_load_dwordx4 %1, %3, off sc0\n\t"
            "s_waitcnt vmcnt(0)"
            : "=&v"(t0), "=&v"(t1)
            : "v"(p0), "v"(p1)
            : "memory");
      } else {
        asm volatile(
            "global_load_dwordx4 %0, %2, off sc0 sc1\n\t"
            "global_load_dwordx4 %1, %3, off sc0 sc1\n\t"
            "s_waitcnt vmcnt(0)"
            : "=&v"(t0), "=&v"(t1)
            : "v"(p0), "v"(p1)
            : "memory");
      }
      *(u32x4*)(Ab + (tid >> 7) * 1032 + (tid & 127) * 8) = t0;
      *(u32x4*)(Ab + ((tid >> 7) + 4) * 1032 + (tid & 127) * 8) = t1;
    }
    __syncthreads();

    // acc init = gx; D layout col=lane&15, row=(lane>>4)*4+r (rows 8-15 dup)
    floatx4 a0, a1 = {}, a2 = {}, a3 = {};
    a0[0] = bf2f(gcur[0]);
    a0[1] = bf2f(gcur[1]);
    a0[2] = bf2f(gcur[2]);
    a0[3] = bf2f(gcur[3]);

    // prefetch gx for t+1: HBM latency hides under the MFMA section
    if (t < 199) {
      const u16* gp = gxb + (size_t)(t + 1) * 262144;
      gcur[0] = gp[0];
      gcur[1] = gp[4096];
      gcur[2] = gp[8192];
      gcur[3] = gp[12288];
    }

    // 4 independent accumulator chains; A rows clamped to 0..7
#pragma unroll
    for (int ks = 0; ks < 32; ks += 4) {
      const u16* ap = Ab + (lrow & 7) * 1032 + ks * 32 + lk8;
      a0 = __builtin_amdgcn_mfma_f32_16x16x32_bf16(*(const bf16x8*)(ap), bfrag[ks], a0, 0, 0, 0);
      a1 = __builtin_amdgcn_mfma_f32_16x16x32_bf16(*(const bf16x8*)(ap + 32), bfrag[ks + 1], a1, 0, 0, 0);
      a2 = __builtin_amdgcn_mfma_f32_16x16x32_bf16(*(const bf16x8*)(ap + 64), bfrag[ks + 2], a2, 0, 0, 0);
      a3 = __builtin_amdgcn_mfma_f32_16x16x32_bf16(*(const bf16x8*)(ap + 96), bfrag[ks + 3], a3, 0, 0, 0);
    }
    const floatx4 acc = (a0 + a1) + (a2 + a3);
    if (lane < 32) {  // rows 0..7 only
      const int mrow = (lane >> 4) * 4;
#pragma unroll
      for (int r = 0; r < 4; ++r)
        gbuf[gate * 256 + (mrow + r) * 32 + half * 16 + lrow] = acc[r];
    }
    __syncthreads();

    // ---- update + publish: waves 0-3 (thread -> batch row tid>>5, col tid&31)
    if (w < 4) {
      const int um = tid >> 5, un = tid & 31;
      const float gi = gbuf[um * 32 + un];
      const float gf = gbuf[256 + um * 32 + un];
      const float gg = gbuf[512 + um * 32 + un];
      const float go = gbuf[768 + um * 32 + un];
      c_state = sigm(gf) * c_state + sigm(gi) * tanhf(gg);
      const float h = sigm(go) * tanhf(c_state);

      const unsigned hb16 = (unsigned)f2bf(h);
      const unsigned nb = (unsigned)__shfl_xor((int)hb16, 1, 64);
      const unsigned lo = (lane & 1) ? (nb | (hb16 << 16)) : (hb16 | (nb << 16));
      const unsigned hi = (unsigned)__shfl_xor((int)lo, 2, 64);
      if ((lane & 3) == 0) {  // 8 words/row, rows 2w (lanes<32) and 2w+1
        const u64 word = (u64)lo | ((u64)hi << 32);
        u64* dst = (u64*)(hseq + (size_t)(t + 1) * 65536 +
                          (size_t)(bb + um) * 1024 + j0) + ((lane & 31) >> 2);
        if (local) {
          *(volatile u64*)dst = word;  // ack = L2 = shared visibility point
        } else {
          u64 old = __hip_atomic_exchange(dst, word, __ATOMIC_RELAXED,
                                          __HIP_MEMORY_SCOPE_AGENT);
          asm volatile("" ::"v"(old));  // force sc0 (returning) form
        }
      }
      asm volatile("s_waitcnt vmcnt(0)" ::: "memory");  // publishes ack'd
    }
    __syncthreads();  // all waves' publishes drained

    if (tid == 0) {
      if (local)
        *(volatile unsigned*)&flags[blockIdx.x] = (unsigned)(t + 1);
      else
        __hip_atomic_store(&flags[blockIdx.x], (unsigned)(t + 1),
                           __ATOMIC_RELAXED, __HIP_MEMORY_SCOPE_AGENT);
    }
  }
}

// ---------------------------------------------------------------------------
// res[b*200+t] = sum_c (stu-nk)*nk*W_out[c] + b_out ; one wave per row.
// ---------------------------------------------------------------------------
__global__ void res_kernel(const float* __restrict__ stu, const float* __restrict__ nk,
                           const float* __restrict__ Wout, const float* __restrict__ bout,
                           float* __restrict__ res) {
  const int row = blockIdx.x * 4 + (threadIdx.x >> 6);
  const int lane = threadIdx.x & 63;
  const float* sp = stu + (size_t)row * 256;
  const float* np = nk + (size_t)row * 256;
  float s = 0.0f;
#pragma unroll
  for (int j = 0; j < 4; ++j) {
    const int c = j * 64 + lane;
    const float nv = np[c];
    s += (sp[c] - nv) * nv * Wout[c];
  }
#pragma unroll
  for (int o = 32; o > 0; o >>= 1) s += __shfl_down(s, o, 64);
  if (lane == 0) res[row] = s + bout[0];
}

// ---------------------------------------------------------------------------
extern "C" void kernel_launch(void* const* d_in, const int* in_sizes, int n_in,
                              void* d_out, int out_size, void* d_ws, size_t ws_size,
                              hipStream_t stream) {
  const float* q_hot = (const float*)d_in[0];
  const int* result = (const int*)d_in[1];
  const float* next_q = (const float*)d_in[2];
  // d_in[3] = concept_num (unused, compile-time constant 256)
  const float* W_kc = (const float*)d_in[4];
  const float* b_kc = (const float*)d_in[5];
  const float* W_ih = (const float*)d_in[6];
  const float* W_hh = (const float*)d_in[7];
  const float* b_ih = (const float*)d_in[8];
  const float* b_hh = (const float*)d_in[9];
  const float* W_state = (const float*)d_in[10];
  const float* b_state = (const float*)d_in[11];
  const float* W_out = (const float*)d_in[12];
  const float* b_out = (const float*)d_in[13];

  float* out_res = (float*)d_out;       // 12800 fp32
  float* out_stu = out_res + 12800;     // 12800*256 fp32

  char* ws = (char*)d_ws;
  u16* kcv = (u16*)(ws);                        // 12800*512 bf16  = 13,107,200 B
  unsigned* dir = (unsigned*)(ws);              // 256 u32 XCD directory --
                                                // ALIASES kcv (dead after the
                                                // gx GEMM); zeroed by init2.
  float* nk = (float*)(ws + 13107200);          // 12800*256 fp32  = 13,107,200 B
  u16* hseq = (u16*)(ws + 26214400);            // 201*65536 bf16  = 26,345,472 B
  u16* Whh_bf = (u16*)(ws + 52559872);          // 4096*1024 bf16  =  8,388,608 B
  u16* Wih_bf = (u16*)(ws + 60948480);          // 4096*512 bf16   =  4,194,304 B
  u16* Wkc_bf = (u16*)(ws + 65142784);          // 256*1024 bf16   =    524,288 B
  u16* Wst_bf = (u16*)(ws + 65667072);          // 256*1024 bf16   =    524,288 B
  unsigned* flags = (unsigned*)(ws + 66191360); // 256 u32 = 1024 B
  u16* gx = (u16*)(ws + 66192384);              // 12800*4096 bf16 = 104,857,600 B
  // q_bf/nq_bf alias the gx region (dead before gx is written)
  u16* q_bf = gx;                               // 12800*1024 bf16 = 26,214,400 B
  u16* nq_bf = gx + 13107200;                   // 12800*1024 bf16
  // total ws footprint: 171,049,984 B

  // fp32 -> bf16 conversions
  cvt_kernel<<<dim3(12800), 256, 0, stream>>>(q_hot, q_bf);
  cvt_kernel<<<dim3(12800), 256, 0, stream>>>(next_q, nq_bf);
  cvt_kernel<<<dim3(256), 256, 0, stream>>>(W_kc, Wkc_bf);
  cvt_kernel<<<dim3(2048), 256, 0, stream>>>(W_ih, Wih_bf);
  cvt_kernel<<<dim3(4096), 256, 0, stream>>>(W_hh, Whh_bf);
  cvt_kernel<<<dim3(256), 256, 0, stream>>>(W_state, Wst_bf);

  init_kernel<<<dim3(64), 256, 0, stream>>>(hseq, flags);
  gemm_bt<EpiKcVec><<<dim3(100, 2), 256, 0, stream>>>(q_bf, Wkc_bf, 12800, 256, 1024,
                                                      EpiKcVec{b_kc, result, kcv});
  gemm_bt<EpiNk><<<dim3(100, 2), 256, 0, stream>>>(nq_bf, Wkc_bf, 12800, 256, 1024,
                                                   EpiNk{b_kc, nk});
  gemm_bt<EpiGx><<<dim3(100, 32), 256, 0, stream>>>(kcv, Wih_bf, 12800, 4096, 512,
                                                    EpiGx{b_ih, b_hh, gx});
  // zero the XCD directory AFTER the gx GEMM consumed kcv (alias!)
  init2_kernel<<<dim3(1), 256, 0, stream>>>(dir);
  lstm_scan<<<dim3(256), 512, 0, stream>>>(Whh_bf, gx, hseq, flags, dir);
  gemm_bt<EpiStu><<<dim3(100, 2), 256, 0, stream>>>(hseq + 65536, Wst_bf, 12800, 256, 1024,
                                                    EpiStu{b_state, out_stu});
  res_kernel<<<dim3(3200), 256, 0, stream>>>(out_stu, nk, W_out, b_out, out_res);
}

// Round 8
// 1716.720 us; speedup vs baseline: 3255.4644x; 3255.4644x over previous
//
#include <hip/hip_runtime.h>
#include <math.h>

// ---------------------------------------------------------------------------
// RNN knowledge-tracing model, MI355X (gfx950).
// B=64, T=200, SKILLS=1024, C=256, H=1024.  ALL external I/O is fp32.
// Internal compute uses bf16 MFMA with fp32 accumulation.
// Round 13: DUAL-CHAIN INTERLEAVING (latency hiding, not reduction).
//   r12 post-mortem: XCD-LOCAL plain-store/sc0 exchange is NOT visible
//   cross-block before L2 eviction -> every poll burned its spin bound
//   (5.6ms, correct only via lock-step staleness).  Abandoned.
//   r5-r11: protocol restructures move +-10%; per-step IC latency is the
//   floor (~4.7us/step for stage-RT + compute + publish-RT + observe).
// This round exploits BATCH-ROW INDEPENDENCE: the 4 chains of 16 batches
// are independent recurrences.  Each block owns TWO chains (A,B) on the
// same 32 columns (same bfrag weights, +3 VGPRs) and alternates phases:
//   S1 stage A(t)   S2 MFMA A   S3 update A   S4 publish A(t+1), poll B>=t
//   S5 stage B(t)   S6 MFMA B   S7 update B   S8 publish B(t+1), poll A>=t+1
// Each chain's poll executes one full opposite-phase (~2us) after the
// matching publish -> the IC round trip is hidden under real compute.
// All pieces are r8-proven: sc0sc1 16B staging, wave0 returning-exchange
// publish + vmcnt + flag store, bounded flag poll.  One Ab buffer reused
// (A's MFMA precedes B's stage overwrite via existing syncs).
// Geometry: 64 blocks x 512 thr = 2 supergroups x 32 col-groups;
// exchange group stays 32 publishers/chain; flags = 4 chains x 32.
// ---------------------------------------------------------------------------

typedef unsigned short u16;
typedef unsigned long long u64;
typedef __bf16 bf16x8 __attribute__((ext_vector_type(8)));
typedef float floatx4 __attribute__((ext_vector_type(4)));
typedef unsigned int u32x4 __attribute__((ext_vector_type(4)));

__device__ __forceinline__ float bf2f(u16 h) {
  unsigned int u = ((unsigned int)h) << 16;
  float f;
  __builtin_memcpy(&f, &u, 4);
  return f;
}
__device__ __forceinline__ u16 f2bf(float f) {
  unsigned int u;
  __builtin_memcpy(&u, &f, 4);
  u += 0x7FFFu + ((u >> 16) & 1u);  // RNE
  return (u16)(u >> 16);
}
__device__ __forceinline__ float sigm(float x) { return 1.0f / (1.0f + __expf(-x)); }

// --- fp32 -> bf16 convert, float4 vectorized; exact grid (n % 1024 == 0) ---
__global__ void cvt_kernel(const float* __restrict__ in, u16* __restrict__ out) {
  const int i = blockIdx.x * 256 + threadIdx.x;
  const float4 v = ((const float4*)in)[i];
  ushort4 o;
  o.x = f2bf(v.x);
  o.y = f2bf(v.y);
  o.z = f2bf(v.z);
  o.w = f2bf(v.w);
  ((ushort4*)out)[i] = o;
}

// ---------------------------------------------------------------------------
// Generic 128x128-tile bf16 GEMM, C = A[M,K] @ B[N,K]^T, epilogue functor.
// ---------------------------------------------------------------------------
template <class Epi>
__global__ __launch_bounds__(256, 2) void gemm_bt(const u16* __restrict__ A,
                                                  const u16* __restrict__ B,
                                                  int M, int N, int K, Epi epi) {
  __shared__ u16 As[128 * 32];
  __shared__ u16 Bs[128 * 32];
  const int tid = threadIdx.x;
  const int w = tid >> 6, lane = tid & 63;
  const int wm = w & 1, wn = w >> 1;
  const int bm = blockIdx.x * 128, bn = blockIdx.y * 128;
  const int lrow = lane & 15, lk8 = (lane >> 4) * 8;
  const int srow = lane >> 2;        // staging: row within 16-row segment
  const int skc = (lane & 3) * 8;    // staging: k chunk (8 bf16 = 16B)

  floatx4 acc[4][4] = {};

  for (int k0 = 0; k0 < K; k0 += 32) {
#pragma unroll
    for (int r = 0; r < 2; ++r) {
      const int seg = w * 2 + r;  // 8 segments of 16 rows x 32 k
      const int row = seg * 16 + srow;
      __builtin_amdgcn_global_load_lds(
          (const __attribute__((address_space(1))) unsigned int*)(A + (size_t)(bm + row) * K + k0 + skc),
          (__attribute__((address_space(3))) unsigned int*)(As + seg * 512), 16, 0, 0);
      __builtin_amdgcn_global_load_lds(
          (const __attribute__((address_space(1))) unsigned int*)(B + (size_t)(bn + row) * K + k0 + skc),
          (__attribute__((address_space(3))) unsigned int*)(Bs + seg * 512), 16, 0, 0);
    }
    __syncthreads();

    bf16x8 af[4], bfr[4];
#pragma unroll
    for (int i = 0; i < 4; ++i) {
      af[i] = *(const bf16x8*)(As + (wm * 64 + i * 16 + lrow) * 32 + lk8);
      bfr[i] = *(const bf16x8*)(Bs + (wn * 64 + i * 16 + lrow) * 32 + lk8);
    }
#pragma unroll
    for (int i = 0; i < 4; ++i)
#pragma unroll
      for (int j = 0; j < 4; ++j)
        acc[i][j] = __builtin_amdgcn_mfma_f32_16x16x32_bf16(af[i], bfr[j], acc[i][j], 0, 0, 0);
    __syncthreads();
  }

  // C/D layout: col = lane&15, row = (lane>>4)*4 + reg  [verified m89/m91]
  const int rbase = bm + wm * 64 + (lane >> 4) * 4;
  const int cbase = bn + wn * 64 + lrow;
#pragma unroll
  for (int i = 0; i < 4; ++i)
#pragma unroll
    for (int j = 0; j < 4; ++j)
#pragma unroll
      for (int r = 0; r < 4; ++r)
        epi(rbase + i * 16 + r, cbase + j * 16, acc[i][j][r]);
}

// --- epilogues --------------------------------------------------------------
struct EpiKcVec {  // rows are b*200+t; scatter into [row][512] by result mask
  const float* bkc;
  const int* result;
  u16* kcv;
  __device__ void operator()(int row, int col, float v) const {
    v += bkc[col];
    const int off = (result[row] == 1) ? 0 : 256;
    const size_t base = (size_t)row * 512;
    kcv[base + off + col] = f2bf(v);
    kcv[base + (256 - off) + col] = 0;  // zero half
  }
};
struct EpiNk {
  const float* bkc;
  float* nk;
  __device__ void operator()(int row, int col, float v) const {
    nk[(size_t)row * 256 + col] = v + bkc[col];
  }
};
struct EpiGx {  // input row = b*200+t -> store t-major (t*64+b), bf16
  const float* bih;
  const float* bhh;
  u16* gx;
  __device__ void operator()(int row, int col, float v) const {
    v += bih[col] + bhh[col];
    const int b = row / 200, t = row - b * 200;
    gx[(size_t)(t * 64 + b) * 4096 + col] = f2bf(v);
  }
};
struct EpiStu {  // input row = t*64+b -> store fp32 at (b*200+t)*256+col
  const float* bst;
  float* out;
  __device__ void operator()(int row, int col, float v) const {
    v += bst[col];
    const int b = row & 63, t = row >> 6;
    out[(size_t)(b * 200 + t) * 256 + col] = v;
  }
};

// ---------------------------------------------------------------------------
// init: zero h frame 0 (64x1024 bf16 = 128KB) + 128 chain flags
// ---------------------------------------------------------------------------
__global__ void init_kernel(u16* hseq, unsigned* flags) {
  const int i = blockIdx.x * 256 + threadIdx.x;  // 64 blocks -> 16384 threads
  ((u64*)hseq)[i] = 0ULL;
  if (blockIdx.x == 0 && threadIdx.x < 128) flags[threadIdx.x] = 0u;
}

// ---------------------------------------------------------------------------
// LSTM scan. 64 blocks x 512 threads = 2 batch-supergroups x 32 col-groups.
// Block owns chains A (rows sg*32..+15) and B (rows sg*32+16..+31) on cols
// j0..j0+31.  Wave w (0..7): gate g = w&3, col-half hf = w>>2; W_hh slice
// (16 rows x 1024 K) in registers as 32 MFMA B-fragments (shared by A,B).
// Per-chain exchange = r8's proven protocol (32 publishers/chain):
//   publish: h tile -> hbuf -> wave0: 128 returning AGENT u64 exchanges;
//            vmcnt(0); lane0 flag store.   wait: wave0 polls 32 peer flags
//            (bounded).   consume: sc0 sc1 16B read-through staging.
// The poll for each chain runs one full opposite-chain phase after the
// matching publish -> IC latency hidden under compute.
// ---------------------------------------------------------------------------
__global__ __launch_bounds__(512, 2) void lstm_scan(const u16* __restrict__ Whh,
                                                    const u16* __restrict__ gx,
                                                    u16* __restrict__ hseq,
                                                    unsigned* __restrict__ flags) {
  __shared__ __align__(16) u16 Ab[16 * 1032];  // +8 pad: 2-way bank alias (free)
  __shared__ float gbuf[4 * 512];
  __shared__ __align__(16) u16 hbuf[16 * 32];
  const int tid = threadIdx.x;
  const int w = tid >> 6;
  const int lane = tid & 63;
  const int lrow = lane & 15;
  const int lk8 = (lane >> 4) * 8;
  const int g = w & 3;    // gate index (torch order i,f,g,o)
  const int hf = w >> 2;  // col half (0/1) within the block's 32 cols
  const int sg = blockIdx.x >> 5;   // batch supergroup (0/1)
  const int cg = blockIdx.x & 31;   // col-group
  const int j0 = cg * 32;
  const int bbA = sg * 32;          // chain A batch rows
  const int bbB = sg * 32 + 16;     // chain B batch rows
  const int fA = (sg * 2 + 0) * 32; // chain A flag base
  const int fB = (sg * 2 + 1) * 32; // chain B flag base

  // B-fragments: W_hh[g*1024 + j0 + hf*16 + lrow][k] -> 128 regs, loaded once
  bf16x8 bfrag[32];
  {
    const u16* wp = Whh + (size_t)(g * 1024 + j0 + hf * 16 + lrow) * 1024 + lk8;
#pragma unroll
    for (int ks = 0; ks < 32; ++ks) bfrag[ks] = *(const bf16x8*)(wp + ks * 32);
  }

  float cA = 0.0f, cB = 0.0f;
  const int um = tid >> 5, un = tid & 31;  // update-phase (batch, col) mapping

  // gx bases: 4 values/thread (batch rows (lane>>4)*4+r, gate g, col hf*16+lrow)
  const u16* gxbA =
      gx + (size_t)(bbA + (lane >> 4) * 4) * 4096 + g * 1024 + j0 + hf * 16 + lrow;
  const u16* gxbB = gxbA + (size_t)16 * 4096;
  u16 gcA[4], gcB[4];
  {
    gcA[0] = gxbA[0];
    gcA[1] = gxbA[4096];
    gcA[2] = gxbA[8192];
    gcA[3] = gxbA[12288];
    gcB[0] = gxbB[0];
    gcB[1] = gxbB[4096];
    gcB[2] = gxbB[8192];
    gcB[3] = gxbB[12288];
  }

  for (int t = 0; t < 200; ++t) {
#pragma unroll
    for (int chain = 0; chain < 2; ++chain) {
      const int bb = chain ? bbB : bbA;
      u16* gc = chain ? gcB : gcA;
      const u16* gxb = chain ? gxbB : gxbA;

      // ---- stage h[t] rows bb..bb+15 (32KB) via coherent 16B loads ----
      {
        const char* hb = (const char*)(hseq + (size_t)t * 65536 + (size_t)bb * 1024);
        const char* p0 = hb + tid * 16;
        const char* p1 = p0 + 8192;
        const char* p2 = p0 + 16384;
        const char* p3 = p0 + 24576;
        u32x4 t0, t1, t2, t3;
        asm volatile(
            "global_load_dwordx4 %0, %4, off sc0 sc1\n\t"
            "global_load_dwordx4 %1, %5, off sc0 sc1\n\t"
            "global_load_dwordx4 %2, %6, off sc0 sc1\n\t"
            "global_load_dwordx4 %3, %7, off sc0 sc1\n\t"
            "s_waitcnt vmcnt(0)"
            : "=&v"(t0), "=&v"(t1), "=&v"(t2), "=&v"(t3)
            : "v"(p0), "v"(p1), "v"(p2), "v"(p3)
            : "memory");
        {
          const int ch = tid;
          *(u32x4*)(Ab + (ch >> 7) * 1032 + (ch & 127) * 8) = t0;
        }
        {
          const int ch = 512 + tid;
          *(u32x4*)(Ab + (ch >> 7) * 1032 + (ch & 127) * 8) = t1;
        }
        {
          const int ch = 1024 + tid;
          *(u32x4*)(Ab + (ch >> 7) * 1032 + (ch & 127) * 8) = t2;
        }
        {
          const int ch = 1536 + tid;
          *(u32x4*)(Ab + (ch >> 7) * 1032 + (ch & 127) * 8) = t3;
        }
      }
      __syncthreads();

      // acc init = gx; D layout col=lane&15, row=(lane>>4)*4+r
      floatx4 a0, a1 = {}, a2 = {}, a3 = {};
      a0[0] = bf2f(gc[0]);
      a0[1] = bf2f(gc[1]);
      a0[2] = bf2f(gc[2]);
      a0[3] = bf2f(gc[3]);

      // prefetch this chain's gx for t+1: hides under the MFMA section
      if (t < 199) {
        const u16* gp = gxb + (size_t)(t + 1) * 262144;
        gc[0] = gp[0];
        gc[1] = gp[4096];
        gc[2] = gp[8192];
        gc[3] = gp[12288];
      }

      // 4 independent accumulator chains (dep chain 32 -> 8)
#pragma unroll
      for (int ks = 0; ks < 32; ks += 4) {
        const u16* ap = Ab + lrow * 1032 + ks * 32 + lk8;
        a0 = __builtin_amdgcn_mfma_f32_16x16x32_bf16(*(const bf16x8*)(ap), bfrag[ks], a0, 0, 0, 0);
        a1 = __builtin_amdgcn_mfma_f32_16x16x32_bf16(*(const bf16x8*)(ap + 32), bfrag[ks + 1], a1, 0, 0, 0);
        a2 = __builtin_amdgcn_mfma_f32_16x16x32_bf16(*(const bf16x8*)(ap + 64), bfrag[ks + 2], a2, 0, 0, 0);
        a3 = __builtin_amdgcn_mfma_f32_16x16x32_bf16(*(const bf16x8*)(ap + 96), bfrag[ks + 3], a3, 0, 0, 0);
      }
      const floatx4 acc = (a0 + a1) + (a2 + a3);
      {
        const int mrow = (lane >> 4) * 4;
#pragma unroll
        for (int r = 0; r < 4; ++r)
          gbuf[g * 512 + (mrow + r) * 32 + hf * 16 + lrow] = acc[r];
      }
      __syncthreads();

      // update: thread -> (batch row um, col un)
      {
        const float gi = gbuf[um * 32 + un];
        const float gf = gbuf[512 + um * 32 + un];
        const float gg = gbuf[1024 + um * 32 + un];
        const float go = gbuf[1536 + um * 32 + un];
        float c = chain ? cB : cA;
        c = sigm(gf) * c + sigm(gi) * tanhf(gg);
        const float h = sigm(go) * tanhf(c);
        if (chain)
          cB = c;
        else
          cA = c;
        hbuf[um * 32 + un] = f2bf(h);
      }
      __syncthreads();

      // ---- wave0: publish h[t+1] (returning exchanges), flag, then the
      //      HIDDEN poll: chain A polls B>=t (licenses next stage B),
      //      chain B polls A>=t+1 (licenses next round's stage A).
      if (tid < 64) {
#pragma unroll
        for (int k = 0; k < 2; ++k) {
          const int wi = k * 64 + lane;  // 128 u64 words (16 rows x 8 words)
          const int row = wi >> 3, cw = wi & 7;
          const u64 v = *(const u64*)(hbuf + row * 32 + cw * 4);
          u64 old = __hip_atomic_exchange(
              (u64*)(hseq + (size_t)(t + 1) * 65536 + (size_t)(bb + row) * 1024 +
                     j0) + cw,
              v, __ATOMIC_RELAXED, __HIP_MEMORY_SCOPE_AGENT);
          asm volatile("" ::"v"(old));  // force sc0 (returning) form
        }
        asm volatile("s_waitcnt vmcnt(0)" ::: "memory");  // returns => at IC
        if (lane == 0)
          __hip_atomic_store(&flags[(chain ? fB : fA) + cg], (unsigned)(t + 1),
                             __ATOMIC_RELAXED, __HIP_MEMORY_SCOPE_AGENT);

        const unsigned tgt = chain ? (unsigned)(t + 1) : (unsigned)t;
        const unsigned* gfp = &flags[(chain ? fA : fB) + (lane & 31)];
        for (unsigned spin = 0; spin < (1u << 20); ++spin) {
          const unsigned v = __hip_atomic_load(gfp, __ATOMIC_RELAXED,
                                               __HIP_MEMORY_SCOPE_AGENT);
          if (__all(v >= tgt)) break;
          __builtin_amdgcn_s_sleep(1);
        }
      }
      __syncthreads();
    }
  }
}

// ---------------------------------------------------------------------------
// res[b*200+t] = sum_c (stu-nk)*nk*W_out[c] + b_out ; one wave per row.
// ---------------------------------------------------------------------------
__global__ void res_kernel(const float* __restrict__ stu, const float* __restrict__ nk,
                           const float* __restrict__ Wout, const float* __restrict__ bout,
                           float* __restrict__ res) {
  const int row = blockIdx.x * 4 + (threadIdx.x >> 6);
  const int lane = threadIdx.x & 63;
  const float* sp = stu + (size_t)row * 256;
  const float* np = nk + (size_t)row * 256;
  float s = 0.0f;
#pragma unroll
  for (int j = 0; j < 4; ++j) {
    const int c = j * 64 + lane;
    const float nv = np[c];
    s += (sp[c] - nv) * nv * Wout[c];
  }
#pragma unroll
  for (int o = 32; o > 0; o >>= 1) s += __shfl_down(s, o, 64);
  if (lane == 0) res[row] = s + bout[0];
}

// ---------------------------------------------------------------------------
extern "C" void kernel_launch(void* const* d_in, const int* in_sizes, int n_in,
                              void* d_out, int out_size, void* d_ws, size_t ws_size,
                              hipStream_t stream) {
  const float* q_hot = (const float*)d_in[0];
  const int* result = (const int*)d_in[1];
  const float* next_q = (const float*)d_in[2];
  // d_in[3] = concept_num (unused, compile-time constant 256)
  const float* W_kc = (const float*)d_in[4];
  const float* b_kc = (const float*)d_in[5];
  const float* W_ih = (const float*)d_in[6];
  const float* W_hh = (const float*)d_in[7];
  const float* b_ih = (const float*)d_in[8];
  const float* b_hh = (const float*)d_in[9];
  const float* W_state = (const float*)d_in[10];
  const float* b_state = (const float*)d_in[11];
  const float* W_out = (const float*)d_in[12];
  const float* b_out = (const float*)d_in[13];

  float* out_res = (float*)d_out;       // 12800 fp32
  float* out_stu = out_res + 12800;     // 12800*256 fp32

  char* ws = (char*)d_ws;
  u16* kcv = (u16*)(ws);                        // 12800*512 bf16  = 13,107,200 B
  float* nk = (float*)(ws + 13107200);          // 12800*256 fp32  = 13,107,200 B
  u16* hseq = (u16*)(ws + 26214400);            // 201*65536 bf16  = 26,345,472 B
  u16* Whh_bf = (u16*)(ws + 52559872);          // 4096*1024 bf16  =  8,388,608 B
  u16* Wih_bf = (u16*)(ws + 60948480);          // 4096*512 bf16   =  4,194,304 B
  u16* Wkc_bf = (u16*)(ws + 65142784);          // 256*1024 bf16   =    524,288 B
  u16* Wst_bf = (u16*)(ws + 65667072);          // 256*1024 bf16   =    524,288 B
  unsigned* flags = (unsigned*)(ws + 66191360); // 128 u32 = 512 B
  u16* gx = (u16*)(ws + 66192384);              // 12800*4096 bf16 = 104,857,600 B
  // q_bf/nq_bf alias the gx region (dead before gx is written)
  u16* q_bf = gx;                               // 12800*1024 bf16 = 26,214,400 B
  u16* nq_bf = gx + 13107200;                   // 12800*1024 bf16
  // total ws footprint: 171,049,984 B

  // fp32 -> bf16 conversions
  cvt_kernel<<<dim3(12800), 256, 0, stream>>>(q_hot, q_bf);
  cvt_kernel<<<dim3(12800), 256, 0, stream>>>(next_q, nq_bf);
  cvt_kernel<<<dim3(256), 256, 0, stream>>>(W_kc, Wkc_bf);
  cvt_kernel<<<dim3(2048), 256, 0, stream>>>(W_ih, Wih_bf);
  cvt_kernel<<<dim3(4096), 256, 0, stream>>>(W_hh, Whh_bf);
  cvt_kernel<<<dim3(256), 256, 0, stream>>>(W_state, Wst_bf);

  init_kernel<<<dim3(64), 256, 0, stream>>>(hseq, flags);
  gemm_bt<EpiKcVec><<<dim3(100, 2), 256, 0, stream>>>(q_bf, Wkc_bf, 12800, 256, 1024,
                                                      EpiKcVec{b_kc, result, kcv});
  gemm_bt<EpiNk><<<dim3(100, 2), 256, 0, stream>>>(nq_bf, Wkc_bf, 12800, 256, 1024,
                                                   EpiNk{b_kc, nk});
  gemm_bt<EpiGx><<<dim3(100, 32), 256, 0, stream>>>(kcv, Wih_bf, 12800, 4096, 512,
                                                    EpiGx{b_ih, b_hh, gx});
  lstm_scan<<<dim3(64), 512, 0, stream>>>(Whh_bf, gx, hseq, flags);
  gemm_bt<EpiStu><<<dim3(100, 2), 256, 0, stream>>>(hseq + 65536, Wst_bf, 12800, 256, 1024,
                                                    EpiStu{b_state, out_stu});
  res_kernel<<<dim3(3200), 256, 0, stream>>>(out_stu, nk, W_out, b_out, out_res);
}